// Round 5
// baseline (358.648 us; speedup 1.0000x reference)
//
#include <hip/hip_runtime.h>
#include <math.h>

#define BSZ    8192
#define DDIM   256
#define SCALE  33.33333333333333f   // 1/0.03
#define C_OFF  34.0f                // fixed LSE offset: |sim*SCALE| <= 33.34
#define SC_L2E 48.08983470f         // SCALE * log2(e)
#define C2     49.05163139f         // C_OFF * log2(e)

typedef __bf16 bf16_t;
typedef __bf16 bf16x8 __attribute__((ext_vector_type(8)));
typedef float  floatx4 __attribute__((ext_vector_type(4)));

__device__ __forceinline__ bf16x8 cvt8(const float* __restrict__ g)
{
    const float4 lo = *(const float4*)g;
    const float4 hi = *(const float4*)(g + 4);
    bf16x8 v;
    v[0] = (bf16_t)lo.x; v[1] = (bf16_t)lo.y; v[2] = (bf16_t)lo.z; v[3] = (bf16_t)lo.w;
    v[4] = (bf16_t)hi.x; v[5] = (bf16_t)hi.y; v[6] = (bf16_t)hi.z; v[7] = (bf16_t)hi.w;
    return v;
}

// ---------------------------------------------------------------- prep
// blocks [0,1024): za -> za_bf (row layout) + zero reduction ws (first 17 blocks)
// blocks [1024,2048): zt -> zt_perm, chunk-ordered: 8KB chunk = (colblock cb, kc);
//   slot P in chunk holds cols cb*128 + (P>>2), k = kc*32 + ((P&3)^(((P>>2)>>1)&3))*8
//   (exactly the LDS image R4's zero-conflict fragment reads expect)
__global__ __launch_bounds__(256) void prep_kernel(
    const float* __restrict__ za, const float* __restrict__ zt,
    bf16_t* __restrict__ za_bf, bf16_t* __restrict__ zt_perm,
    float* __restrict__ zbase)
{
    const int bid = blockIdx.x, tid = threadIdx.x;
    if (bid < 1024) {
        const int i = (bid * 256 + tid) * 8;
        *(bf16x8*)&za_bf[i] = cvt8(za + i);
        if (bid < 16) {
            const int z = bid * 1024 + tid * 4;
            *(float4*)&zbase[z] = (float4){0.f, 0.f, 0.f, 0.f};
            if (bid == 0 && tid == 0) {
                zbase[16384] = 0.f;          // total
                ((int*)zbase)[16385] = 0;    // flag
                ((int*)zbase)[16386] = 0;    // cnt
            }
        }
    } else {
        const int S     = (bid - 1024) * 256 + tid;   // global 16B-slot id
        const int chunk = S >> 9, P = S & 511;
        const int col   = P >> 2, sp = P & 3;
        const int sl    = sp ^ ((col >> 1) & 3);
        const int cb    = chunk >> 3, kc = chunk & 7;
        const float* src = zt + (size_t)(cb * 128 + col) * DDIM + kc * 32 + sl * 8;
        *(bf16x8*)(zt_perm + (size_t)S * 8) = cvt8(src);
    }
}

// ---------------------------------------------------------------- sim
// Grid: 64 bands x 16 strips = 1024 blocks, 4 waves. Wave w: rows [band*128+32w,+32),
// A (full K=256) resident in VGPRs. Strip = 512 cols = 4 tiles of 128; B staged
// bf16 via fire-and-forget global_load_lds from zt_perm (1KB/issue, dbuf,
// 1 barrier/chunk). Fused epilogue: mask+exp2+row/col sums, uniform diag fixup.
__global__ __launch_bounds__(256, 2) void sim_fused(
    const bf16_t* __restrict__ za_bf, const bf16_t* __restrict__ zt_perm,
    const int* __restrict__ pid,
    float* __restrict__ s_row, float* __restrict__ s_col,
    float* __restrict__ posv)
{
    __shared__ __align__(16) bf16_t Bs[2][128 * 32];   // 2 x 8 KB
    __shared__ int   pidc[512];
    __shared__ float colsum[512];

    const int bid   = blockIdx.x;
    const int strip = bid & 15, band = bid >> 4;
    const int row0  = band * 128, scol0 = strip * 512;
    const int tid   = threadIdx.x, lane = tid & 63, wid = tid >> 6;
    const int q     = lane >> 4, lc = lane & 15;
    const int rbase = row0 + wid * 32;

    pidc[tid]         = pid[scol0 + tid];
    pidc[tid + 256]   = pid[scol0 + tid + 256];
    colsum[tid]       = 0.f;
    colsum[tid + 256] = 0.f;

    // A fragments resident: af[m][kc] = A[rbase+m*16+lc][kc*32 + q*8 ..+8]
    bf16x8 af[2][8];
    #pragma unroll
    for (int m = 0; m < 2; m++) {
        const bf16_t* ga = za_bf + (size_t)(rbase + m * 16 + lc) * DDIM + q * 8;
        #pragma unroll
        for (int kc = 0; kc < 8; kc++)
            af[m][kc] = *(const bf16x8*)(ga + kc * 32);
    }

    // row pids in registers
    int prw[2][4];
    #pragma unroll
    for (int m = 0; m < 2; m++)
        #pragma unroll
        for (int r = 0; r < 4; r++)
            prw[m][r] = pid[rbase + m * 16 + q * 4 + r];

    // staging: chunk g of this strip = zt_perm bytes [(strip*32+g)*8192, +8192)
    // per-lane src offset (wid*64+lane)*16 and +4096; LDS dst wave-uniform.
    const char* zp = (const char*)zt_perm + (size_t)(strip * 32) * 8192
                   + (wid * 64 + lane) * 16;

#define STAGE(g, b)                                                              \
    do {                                                                         \
        const char* _s = zp + (size_t)(g) * 8192;                                \
        char* _d = (char*)Bs[b] + wid * 1024;                                    \
        __builtin_amdgcn_global_load_lds(                                        \
            (const __attribute__((address_space(1))) void*)_s,                   \
            (__attribute__((address_space(3))) void*)_d, 16, 0, 0);              \
        __builtin_amdgcn_global_load_lds(                                        \
            (const __attribute__((address_space(1))) void*)(_s + 4096),          \
            (__attribute__((address_space(3))) void*)(_d + 4096), 16, 0, 0);     \
    } while (0)

    STAGE(0, 0);   // prologue

    float rowp[8] = {0.f, 0.f, 0.f, 0.f, 0.f, 0.f, 0.f, 0.f};
    const int diag_t = (row0 - scol0) >> 7;   // tile index holding the diagonal (if in [0,4))
    const int xoff   = (lc >> 1) & 3;

    for (int t = 0; t < 4; t++) {
        floatx4 acc[2][8];
        #pragma unroll
        for (int m = 0; m < 2; m++)
            #pragma unroll
            for (int n = 0; n < 8; n++)
                acc[m][n] = (floatx4){0.f, 0.f, 0.f, 0.f};

        #pragma unroll
        for (int kc = 0; kc < 8; kc++) {
            __syncthreads();                 // chunk g landed (vmcnt drain at barrier)
            const int g = t * 8 + kc;
            if (g + 1 < 32) STAGE(g + 1, (g + 1) & 1);   // fire-and-forget prefetch

            const char* B = (const char*)Bs[g & 1];
            bf16x8 bfr[8];
            #pragma unroll
            for (int n = 0; n < 8; n++)
                bfr[n] = *(const bf16x8*)(B + (n * 16 + lc) * 64 + ((q ^ xoff) * 16));

            #pragma unroll
            for (int m = 0; m < 2; m++)
                #pragma unroll
                for (int n = 0; n < 8; n++)
                    acc[m][n] = __builtin_amdgcn_mfma_f32_16x16x32_bf16(
                        af[m][kc], bfr[n], acc[m][n], 0, 0, 0);
        }

        // ---------- epilogue for tile t (overlaps next tile's in-flight prefetch)
        int pc[8];
        #pragma unroll
        for (int n = 0; n < 8; n++) pc[n] = pidc[t * 128 + n * 16 + lc];

        float colp[8] = {0.f, 0.f, 0.f, 0.f, 0.f, 0.f, 0.f, 0.f};
        #pragma unroll
        for (int m = 0; m < 2; m++) {
            #pragma unroll
            for (int r = 0; r < 4; r++) {
                const int pr = prw[m][r];
                float rsum = 0.f;
                #pragma unroll
                for (int n = 0; n < 8; n++) {
                    float e = __builtin_amdgcn_exp2f(fmaf(acc[m][n][r], SC_L2E, -C2));
                    e = (pr != pc[n]) ? e : 0.f;
                    rsum += e;
                    colp[n] += e;
                }
                rowp[m * 4 + r] += rsum;
            }
        }

        if (t == diag_t) {   // uniform branch: add back the (always same-pid) diagonal
            #pragma unroll
            for (int m = 0; m < 2; m++) {
                #pragma unroll
                for (int r = 0; r < 4; r++) {
                    const int nstar = wid * 2 + m;
                    const float v = acc[m][nstar][r];
                    float e = __builtin_amdgcn_exp2f(fmaf(v, SC_L2E, -C2));
                    const bool own = (lc == q * 4 + r);
                    e = own ? e : 0.f;
                    rowp[m * 4 + r] += e;
                    colp[nstar] += e;
                    if (own) posv[rbase + m * 16 + q * 4 + r] = v * SCALE;
                }
            }
        }

        #pragma unroll
        for (int n = 0; n < 8; n++) {
            colp[n] += __shfl_xor(colp[n], 16, 64);
            colp[n] += __shfl_xor(colp[n], 32, 64);
        }
        if (q == 0) {
            #pragma unroll
            for (int n = 0; n < 8; n++)
                atomicAdd(&colsum[t * 128 + n * 16 + lc], colp[n]);
        }
    }

    // ---------- row sums: reduce over lc (cols), one atomic per row
    #pragma unroll
    for (int i = 0; i < 8; i++) {
        rowp[i] += __shfl_xor(rowp[i], 1, 64);
        rowp[i] += __shfl_xor(rowp[i], 2, 64);
        rowp[i] += __shfl_xor(rowp[i], 4, 64);
        rowp[i] += __shfl_xor(rowp[i], 8, 64);
    }
    float rw = rowp[0];
    #pragma unroll
    for (int idx = 1; idx < 8; idx++)
        rw = (lc == idx) ? rowp[idx] : rw;
    if (lc < 8)
        atomicAdd(&s_row[rbase + (lc >> 2) * 16 + q * 4 + (lc & 3)], rw);

    // ---------- col sums
    __syncthreads();
    atomicAdd(&s_col[scol0 + tid], colsum[tid]);
    atomicAdd(&s_col[scol0 + tid + 256], colsum[tid + 256]);
#undef STAGE
}

// ---------------------------------------------------------------- finalize (+ scalar write)
__global__ __launch_bounds__(256) void finalize_rows(
    const int* __restrict__ pid,
    const float* __restrict__ s_row, const float* __restrict__ s_col,
    const float* __restrict__ posv,
    float* __restrict__ total, int* __restrict__ flag, int* __restrict__ cnt,
    float* __restrict__ out)
{
    const int i = blockIdx.x * 256 + threadIdx.x;
    const float p = posv[i];
    const float c = (logf(s_row[i]) + C_OFF - p)
                  + (logf(s_col[i]) + C_OFF - p);

    float v = c;
    #pragma unroll
    for (int off = 32; off > 0; off >>= 1) v += __shfl_down(v, off, 64);
    if ((threadIdx.x & 63) == 0) atomicAdd(total, v);

    const unsigned long long m = __ballot(pid[i] != pid[0]);
    if (m != 0ull && (threadIdx.x & 63) == 0) atomicOr(flag, 1);

    __syncthreads();
    __threadfence();
    if (threadIdx.x == 0) {
        const int done = atomicAdd(cnt, 1);
        if (done == (int)gridDim.x - 1) {
            const float t = atomicAdd(total, 0.0f);
            const int   f = atomicOr(flag, 0);
            out[0] = f ? t / (2.0f * (float)BSZ) : 0.0f;
        }
    }
}

// ---------------------------------------------------------------- launcher
extern "C" void kernel_launch(void* const* d_in, const int* in_sizes, int n_in,
                              void* d_out, int out_size, void* d_ws, size_t ws_size,
                              hipStream_t stream)
{
    const float* za  = (const float*)d_in[0];
    const float* zt  = (const float*)d_in[1];
    const int*   pid = (const int*)d_in[2];
    float* out = (float*)d_out;

    // ws: za_bf 4MB | zt_perm 4MB | s_row[8192] s_col[8192] total flag cnt posv[8192]
    bf16_t* za_bf   = (bf16_t*)d_ws;
    bf16_t* zt_perm = za_bf + (size_t)BSZ * DDIM;
    float*  s_row   = (float*)(zt_perm + (size_t)BSZ * DDIM);
    float*  s_col   = s_row + BSZ;
    float*  total   = s_col + BSZ;
    int*    flag    = (int*)(total + 1);
    int*    cnt     = flag + 1;
    float*  posv    = (float*)(cnt + 1);

    prep_kernel<<<dim3(2048), 256, 0, stream>>>(za, zt, za_bf, zt_perm, s_row);

    sim_fused<<<dim3(1024), 256, 0, stream>>>(za_bf, zt_perm, pid,
                                              s_row, s_col, posv);

    finalize_rows<<<dim3(BSZ / 256), 256, 0, stream>>>(
        pid, s_row, s_col, posv, total, flag, cnt, out);
}

// Round 6
// 129.984 us; speedup vs baseline: 2.7592x; 2.7592x over previous
//
#include <hip/hip_runtime.h>
#include <math.h>

#define BSZ    8192
#define DDIM   256
#define SCALE  33.33333333333333f   // 1/0.03
#define C_OFF  34.0f                // fixed LSE offset: |sim*SCALE| <= 33.34
#define SC_L2E 48.08983470f         // SCALE * log2(e)
#define C2     49.05163139f         // C_OFF * log2(e)

typedef __bf16 bf16_t;
typedef __bf16 bf16x8 __attribute__((ext_vector_type(8)));
typedef float  floatx4 __attribute__((ext_vector_type(4)));

__device__ __forceinline__ bf16x8 cvt8(const float* __restrict__ g)
{
    const float4 lo = *(const float4*)g;
    const float4 hi = *(const float4*)(g + 4);
    bf16x8 v;
    v[0] = (bf16_t)lo.x; v[1] = (bf16_t)lo.y; v[2] = (bf16_t)lo.z; v[3] = (bf16_t)lo.w;
    v[4] = (bf16_t)hi.x; v[5] = (bf16_t)hi.y; v[6] = (bf16_t)hi.z; v[7] = (bf16_t)hi.w;
    return v;
}

// ---------------------------------------------------------------- prep
// blocks [0,1024): za -> za_bf (row layout) + zero reduction ws (first 17 blocks)
// blocks [1024,2048): zt -> zt_perm, chunk-ordered: 8KB chunk = (colblock cb, kc);
//   slot P in chunk holds col cb*128 + (P>>2), k = kc*32 + ((P&3)^(((P>>2)>>1)&3))*8
__global__ __launch_bounds__(256) void prep_kernel(
    const float* __restrict__ za, const float* __restrict__ zt,
    bf16_t* __restrict__ za_bf, bf16_t* __restrict__ zt_perm,
    float* __restrict__ zbase)
{
    const int bid = blockIdx.x, tid = threadIdx.x;
    if (bid < 1024) {
        const int i = (bid * 256 + tid) * 8;
        *(bf16x8*)&za_bf[i] = cvt8(za + i);
        if (bid < 16) {
            const int z = bid * 1024 + tid * 4;
            *(float4*)&zbase[z] = (float4){0.f, 0.f, 0.f, 0.f};
            if (bid == 0 && tid == 0) {
                zbase[16384] = 0.f;          // total
                ((int*)zbase)[16385] = 0;    // flag
                ((int*)zbase)[16386] = 0;    // cnt
            }
        }
    } else {
        const int S     = (bid - 1024) * 256 + tid;   // global 16B-slot id
        const int chunk = S >> 9, P = S & 511;
        const int col   = P >> 2, sp = P & 3;
        const int sl    = sp ^ ((col >> 1) & 3);
        const int cb    = chunk >> 3, kc = chunk & 7;
        const float* src = zt + (size_t)(cb * 128 + col) * DDIM + kc * 32 + sl * 8;
        *(bf16x8*)(zt_perm + (size_t)S * 8) = cvt8(src);
    }
}

// ---------------------------------------------------------------- sim
// Grid: 64 bands x 16 strips = 1024 blocks, 4 waves. Wave w: rows [band*128+32w,+32),
// A (full K=256) resident in VGPRs. Strip = 512 cols = 4 tiles of 128; B staged
// bf16 via fire-and-forget global_load_lds from zt_perm (1KB/issue, dbuf,
// 1 barrier/chunk). Fused epilogue: mask+exp2+row/col sums, uniform diag fixup.
// NOTE: no dynamic indexing into register arrays anywhere (R5's scratch-spill bug).
__global__ __launch_bounds__(256, 2) void sim_fused(
    const bf16_t* __restrict__ za_bf, const bf16_t* __restrict__ zt_perm,
    const int* __restrict__ pid,
    float* __restrict__ s_row, float* __restrict__ s_col,
    float* __restrict__ posv)
{
    __shared__ __align__(16) bf16_t Bs[2][128 * 32];   // 2 x 8 KB
    __shared__ int   pidc[512];
    __shared__ float colsum[512];

    const int bid   = blockIdx.x;
    const int strip = bid & 15, band = bid >> 4;
    const int row0  = band * 128, scol0 = strip * 512;
    const int tid   = threadIdx.x, lane = tid & 63, wid = tid >> 6;
    const int q     = lane >> 4, lc = lane & 15;
    const int rbase = row0 + wid * 32;

    pidc[tid]         = pid[scol0 + tid];
    pidc[tid + 256]   = pid[scol0 + tid + 256];
    colsum[tid]       = 0.f;
    colsum[tid + 256] = 0.f;

    // A fragments resident: af[m][kc] = A[rbase+m*16+lc][kc*32 + q*8 ..+8]
    bf16x8 af[2][8];
    #pragma unroll
    for (int m = 0; m < 2; m++) {
        const bf16_t* ga = za_bf + (size_t)(rbase + m * 16 + lc) * DDIM + q * 8;
        #pragma unroll
        for (int kc = 0; kc < 8; kc++)
            af[m][kc] = *(const bf16x8*)(ga + kc * 32);
    }

    // row pids in registers
    int prw[2][4];
    #pragma unroll
    for (int m = 0; m < 2; m++)
        #pragma unroll
        for (int r = 0; r < 4; r++)
            prw[m][r] = pid[rbase + m * 16 + q * 4 + r];

    // staging: chunk g of this strip = zt_perm bytes [(strip*32+g)*8192, +8192)
    const char* zp = (const char*)zt_perm + (size_t)(strip * 32) * 8192
                   + (wid * 64 + lane) * 16;

#define STAGE(g, b)                                                              \
    do {                                                                         \
        const char* _s = zp + (size_t)(g) * 8192;                                \
        char* _d = (char*)Bs[b] + wid * 1024;                                    \
        __builtin_amdgcn_global_load_lds(                                        \
            (const __attribute__((address_space(1))) void*)_s,                   \
            (__attribute__((address_space(3))) void*)_d, 16, 0, 0);              \
        __builtin_amdgcn_global_load_lds(                                        \
            (const __attribute__((address_space(1))) void*)(_s + 4096),          \
            (__attribute__((address_space(3))) void*)(_d + 4096), 16, 0, 0);     \
    } while (0)

    STAGE(0, 0);   // prologue

    float rowp[8] = {0.f, 0.f, 0.f, 0.f, 0.f, 0.f, 0.f, 0.f};
    const int diag_t = (row0 - scol0) >> 7;   // tile index holding the diagonal (if in [0,4))
    const int xoff   = (lc >> 1) & 3;

    for (int t = 0; t < 4; t++) {
        floatx4 acc[2][8];
        #pragma unroll
        for (int m = 0; m < 2; m++)
            #pragma unroll
            for (int n = 0; n < 8; n++)
                acc[m][n] = (floatx4){0.f, 0.f, 0.f, 0.f};

        #pragma unroll
        for (int kc = 0; kc < 8; kc++) {
            __syncthreads();                 // chunk g landed (vmcnt drain at barrier)
            const int g = t * 8 + kc;
            if (g + 1 < 32) STAGE(g + 1, (g + 1) & 1);   // fire-and-forget prefetch

            const char* B = (const char*)Bs[g & 1];
            bf16x8 bfr[8];
            #pragma unroll
            for (int n = 0; n < 8; n++)
                bfr[n] = *(const bf16x8*)(B + (n * 16 + lc) * 64 + ((q ^ xoff) * 16));

            #pragma unroll
            for (int m = 0; m < 2; m++)
                #pragma unroll
                for (int n = 0; n < 8; n++)
                    acc[m][n] = __builtin_amdgcn_mfma_f32_16x16x32_bf16(
                        af[m][kc], bfr[n], acc[m][n], 0, 0, 0);
        }

        // ---------- epilogue for tile t (overlaps next tile's in-flight prefetch)
        int pc[8];
        #pragma unroll
        for (int n = 0; n < 8; n++) pc[n] = pidc[t * 128 + n * 16 + lc];

        float colp[8] = {0.f, 0.f, 0.f, 0.f, 0.f, 0.f, 0.f, 0.f};
        #pragma unroll
        for (int m = 0; m < 2; m++) {
            #pragma unroll
            for (int r = 0; r < 4; r++) {
                const int pr = prw[m][r];
                float rsum = 0.f;
                #pragma unroll
                for (int n = 0; n < 8; n++) {
                    float e = __builtin_amdgcn_exp2f(fmaf(acc[m][n][r], SC_L2E, -C2));
                    e = (pr != pc[n]) ? e : 0.f;
                    rsum += e;
                    colp[n] += e;
                }
                rowp[m * 4 + r] += rsum;
            }
        }

        if (t == diag_t) {   // uniform branch: add back the (same-pid) diagonal.
            // CONSTANT-INDEX select chains only — dynamic reg-array indexing
            // demotes acc[] to scratch (R5: 1.66 GB HBM writes, 3x regression).
            #pragma unroll
            for (int m = 0; m < 2; m++) {
                const int nstar = wid * 2 + m;          // runtime value, fine
                #pragma unroll
                for (int r = 0; r < 4; r++) {
                    float v = 0.f;
                    #pragma unroll
                    for (int n = 0; n < 8; n++)
                        v = (n == nstar) ? acc[m][n][r] : v;   // cndmask chain
                    float e = __builtin_amdgcn_exp2f(fmaf(v, SC_L2E, -C2));
                    const bool own = (lc == q * 4 + r);
                    e = own ? e : 0.f;
                    rowp[m * 4 + r] += e;
                    #pragma unroll
                    for (int n = 0; n < 8; n++)
                        colp[n] += (n == nstar) ? e : 0.f;     // cndmask chain
                    if (own) posv[rbase + m * 16 + q * 4 + r] = v * SCALE;
                }
            }
        }

        #pragma unroll
        for (int n = 0; n < 8; n++) {
            colp[n] += __shfl_xor(colp[n], 16, 64);
            colp[n] += __shfl_xor(colp[n], 32, 64);
        }
        if (q == 0) {
            #pragma unroll
            for (int n = 0; n < 8; n++)
                atomicAdd(&colsum[t * 128 + n * 16 + lc], colp[n]);
        }
    }

    // ---------- row sums: reduce over lc (cols), one atomic per row
    #pragma unroll
    for (int i = 0; i < 8; i++) {
        rowp[i] += __shfl_xor(rowp[i], 1, 64);
        rowp[i] += __shfl_xor(rowp[i], 2, 64);
        rowp[i] += __shfl_xor(rowp[i], 4, 64);
        rowp[i] += __shfl_xor(rowp[i], 8, 64);
    }
    float rw = rowp[0];
    #pragma unroll
    for (int idx = 1; idx < 8; idx++)
        rw = (lc == idx) ? rowp[idx] : rw;
    if (lc < 8)
        atomicAdd(&s_row[rbase + (lc >> 2) * 16 + q * 4 + (lc & 3)], rw);

    // ---------- col sums
    __syncthreads();
    atomicAdd(&s_col[scol0 + tid], colsum[tid]);
    atomicAdd(&s_col[scol0 + tid + 256], colsum[tid + 256]);
#undef STAGE
}

// ---------------------------------------------------------------- finalize (+ scalar write)
__global__ __launch_bounds__(256) void finalize_rows(
    const int* __restrict__ pid,
    const float* __restrict__ s_row, const float* __restrict__ s_col,
    const float* __restrict__ posv,
    float* __restrict__ total, int* __restrict__ flag, int* __restrict__ cnt,
    float* __restrict__ out)
{
    const int i = blockIdx.x * 256 + threadIdx.x;
    const float p = posv[i];
    const float c = (logf(s_row[i]) + C_OFF - p)
                  + (logf(s_col[i]) + C_OFF - p);

    float v = c;
    #pragma unroll
    for (int off = 32; off > 0; off >>= 1) v += __shfl_down(v, off, 64);
    if ((threadIdx.x & 63) == 0) atomicAdd(total, v);

    const unsigned long long m = __ballot(pid[i] != pid[0]);
    if (m != 0ull && (threadIdx.x & 63) == 0) atomicOr(flag, 1);

    __syncthreads();
    __threadfence();
    if (threadIdx.x == 0) {
        const int done = atomicAdd(cnt, 1);
        if (done == (int)gridDim.x - 1) {
            const float t = atomicAdd(total, 0.0f);
            const int   f = atomicOr(flag, 0);
            out[0] = f ? t / (2.0f * (float)BSZ) : 0.0f;
        }
    }
}

// ---------------------------------------------------------------- launcher
extern "C" void kernel_launch(void* const* d_in, const int* in_sizes, int n_in,
                              void* d_out, int out_size, void* d_ws, size_t ws_size,
                              hipStream_t stream)
{
    const float* za  = (const float*)d_in[0];
    const float* zt  = (const float*)d_in[1];
    const int*   pid = (const int*)d_in[2];
    float* out = (float*)d_out;

    // ws: za_bf 4MB | zt_perm 4MB | s_row[8192] s_col[8192] total flag cnt posv[8192]
    bf16_t* za_bf   = (bf16_t*)d_ws;
    bf16_t* zt_perm = za_bf + (size_t)BSZ * DDIM;
    float*  s_row   = (float*)(zt_perm + (size_t)BSZ * DDIM);
    float*  s_col   = s_row + BSZ;
    float*  total   = s_col + BSZ;
    int*    flag    = (int*)(total + 1);
    int*    cnt     = flag + 1;
    float*  posv    = (float*)(cnt + 1);

    prep_kernel<<<dim3(2048), 256, 0, stream>>>(za, zt, za_bf, zt_perm, s_row);

    sim_fused<<<dim3(1024), 256, 0, stream>>>(za_bf, zt_perm, pid,
                                              s_row, s_col, posv);

    finalize_rows<<<dim3(BSZ / 256), 256, 0, stream>>>(
        pid, s_row, s_col, posv, total, flag, cnt, out);
}